// Round 11
// baseline (307.253 us; speedup 1.0000x reference)
//
#include <hip/hip_runtime.h>
#include <hip/hip_bf16.h>

#define NROWS 4096
#define NCLS  10000
#define DIM   2048
#define DIMB  1024          // bytes per row in fp4
#define ALPHA_F 10.0f
#define BETA_F  2.0f
#define FP4_SCALE 64.0f
#define INVQ (1.0f / (FP4_SCALE * FP4_SCALE))   // undo scale^2 on dot products
#define NMAIN_BLK 2560      // 80 col-tiles x 32 row-tiles
#define NSIM_BLK  528       // 32*33/2 triangle

typedef float f32x4 __attribute__((ext_vector_type(4)));
typedef int   i32x4 __attribute__((ext_vector_type(4)));
typedef int   i32x8 __attribute__((ext_vector_type(8)));

// f32 -> fp4 e2m1 RNE (code 0..7 = {0,0.5,1,1.5,2,3,4,6}, bit3 = sign),
// pre-scaled by FP4_SCALE, 8 elems -> 1 u32 of nibbles. X and Kn in one launch.
__global__ void cast_fp4_kernel(const float* __restrict__ X, const float* __restrict__ Kn,
                                unsigned int* __restrict__ dA, unsigned int* __restrict__ dB,
                                int nA8, int nT8) {
  int stride = gridDim.x * blockDim.x;
  for (int i = blockIdx.x * blockDim.x + threadIdx.x; i < nT8; i += stride) {
    const float* src; unsigned int* dst; int j;
    if (i < nA8) { src = X; dst = dA; j = i; } else { src = Kn; dst = dB; j = i - nA8; }
    float4 a = reinterpret_cast<const float4*>(src)[2 * j];
    float4 b = reinterpret_cast<const float4*>(src)[2 * j + 1];
    float v[8] = {a.x, a.y, a.z, a.w, b.x, b.y, b.z, b.w};
    unsigned int w = 0;
#pragma unroll
    for (int q = 0; q < 8; ++q) {
      float s = v[q] * FP4_SCALE;
      float av = fabsf(s);
      unsigned int code = (unsigned)(av > 0.25f) + (av > 0.75f) + (av > 1.25f)
                        + (av > 1.75f) + (av > 2.5f) + (av > 3.5f) + (av > 5.0f);
      code |= (s < 0.f) ? 8u : 0u;
      w |= code << (4 * q);
    }
    dst[j] = w;
  }
}

// fp32 dot(inputs_i, kernel[targets_i]) -> dotv[i]; one wave per row. Exact path.
__global__ void gather_dot_kernel(const float* __restrict__ X, const float* __restrict__ Kn,
                                  const int* __restrict__ tgt, float* __restrict__ dotv) {
  int gtid = blockIdx.x * blockDim.x + threadIdx.x;
  int wave = gtid >> 6;
  int lane = threadIdx.x & 63;
  if (wave >= NROWS) return;
  const float* xr = X + (size_t)wave * DIM;
  const float* kr = Kn + (size_t)tgt[wave] * DIM;
  float s = 0.f;
#pragma unroll
  for (int it = 0; it < DIM / 256; ++it) {
    int k = lane * 4 + it * 256;
    float4 a = *reinterpret_cast<const float4*>(xr + k);
    float4 b = *reinterpret_cast<const float4*>(kr + k);
    s += a.x * b.x + a.y * b.y + a.z * b.z + a.w * b.w;
  }
#pragma unroll
  for (int off = 32; off > 0; off >>= 1) s += __shfl_down(s, off);
  if (lane == 0) dotv[wave] = s;
}

// ---------------------------------------------------------------------------
// Merged 128x128 MX-fp4 (e2m1, unit scales) K=128 MFMA A*B^T with fused
// reduction epilogues; ONE dispatch covers the n x C GEMM (blocks < 2560)
// and the lower-triangle sim GEMM (blocks >= 2560) so sim blocks fill the
// main GEMM's tail. 256 threads = 4 waves (2x2, 64x64 each), BK=128,
// dbuf 16KB tiles -> 32KB LDS -> 5 blocks/CU (160KB exactly).
// LDS geometry (measured-zero-conflict family of rounds 2-5/9): row pairs
// packed into 128B lines; line l holds rows {2l, 2l+1}; phys 16B slot8 =
// logical8 ^ (l&7), logical8 = (row&1)*4 + col16. Inverse pre-applied on the
// gload SOURCE address; gload dest stays linear (rule 21). Frag read: 8
// lanes per line cover all 8 slots exactly once -> uniform 8 words/bank.
// Staging addresses fully hoisted: per-thread row/clamp/base pointers and
// dests computed once; per-iter stage = shift-add + 4 global_load_lds.
// ---------------------------------------------------------------------------

#define AS1 const __attribute__((address_space(1))) void*
#define AS3 __attribute__((address_space(3))) void*

__global__ __launch_bounds__(256, 5)
void gemm_kernel(const unsigned char* __restrict__ A,
                 const unsigned char* __restrict__ Bm,
                 const float* __restrict__ dotv,
                 const int* __restrict__ tgt,
                 float* __restrict__ S1, float* __restrict__ Eacc,
                 float* __restrict__ CNT, float* __restrict__ simAcc) {
  __shared__ unsigned char lds[2 * 16384];   // 2 bufs x (A 8KB + B 8KB)

  const int tid  = threadIdx.x;
  const int lane = tid & 63;
  const int wid  = tid >> 6;
  const int wr   = wid >> 1;       // 0..1
  const int wc   = wid & 1;        // 0..1
  const int fr   = lane & 15;
  const int kg   = lane >> 4;      // K-block 0..3 (32 elems = 16B) within K=128

  // block role + XCD-aware swizzle (both sub-grids are multiples of 8)
  const int lin = blockIdx.x;
  const bool isMain = lin < NMAIN_BLK;
  int rowTile, colTile, nB;
  const unsigned char* B;
  if (isMain) {
    int swz = (lin & 7) * 320 + (lin >> 3);  // cpx=320; col-major chunks
    colTile = swz / 32;                      // 10 col-panels per XCD
    rowTile = swz % 32;
    B = Bm; nB = NCLS;
  } else {
    int l2 = lin - NMAIN_BLK;
    int swz = (l2 & 7) * 66 + (l2 >> 3);     // cpx=66; triangle
    int r = 0;
    while ((r + 1) * (r + 2) / 2 <= swz) ++r;
    rowTile = r;
    colTile = swz - r * (r + 1) / 2;
    B = A; nB = NROWS;
  }
  const int rowBase = rowTile * 128;
  const int colBase = colTile * 128;

  // ---- staging precompute (kt-invariant) ----
  const int l0  = tid >> 3;                  // line within 32-line quarter
  const int sp  = tid & 7;                   // phys slot
  const int lg8 = sp ^ (l0 & 7);             // logical slot (l&7 == l0&7 for both quarters)
  const int shi = lg8 >> 2, sc16 = lg8 & 3;
  const int rA0 = rowBase + 2 * l0 + shi;            // A never clamps (rowBase+127 < 4096)
  const int rA1 = rA0 + 64;
  int cB0 = colBase + 2 * l0 + shi;      if (cB0 > nB - 1) cB0 = nB - 1;
  int cB1 = colBase + 64 + 2 * l0 + shi; if (cB1 > nB - 1) cB1 = nB - 1;
  const unsigned char* pA0 = A + (size_t)rA0 * DIMB + sc16 * 16;
  const unsigned char* pA1 = A + (size_t)rA1 * DIMB + sc16 * 16;
  const unsigned char* pB0 = B + (size_t)cB0 * DIMB + sc16 * 16;
  const unsigned char* pB1 = B + (size_t)cB1 * DIMB + sc16 * 16;
  const int dOff = l0 * 128 + sp * 16;       // linear LDS dest (per quarter base added)

#define STAGE_TILE(BUF, KT)                                                     \
  { int ko_ = (KT) * 64;                                                        \
    unsigned char* d_ = lds + (BUF) * 16384 + dOff;                             \
    __builtin_amdgcn_global_load_lds((AS1)(pA0 + ko_), (AS3)(d_),          16, 0, 0); \
    __builtin_amdgcn_global_load_lds((AS1)(pA1 + ko_), (AS3)(d_ + 4096),   16, 0, 0); \
    __builtin_amdgcn_global_load_lds((AS1)(pB0 + ko_), (AS3)(d_ + 8192),   16, 0, 0); \
    __builtin_amdgcn_global_load_lds((AS1)(pB1 + ko_), (AS3)(d_ + 12288),  16, 0, 0); }

  // ---- fragment-read offsets (kt-invariant, fully unrolled -> registers) ----
  int offA[4], offB[4];
#pragma unroll
  for (int m2 = 0; m2 < 4; ++m2) {
    int lr = wr * 64 + m2 * 16 + fr;
    int l = lr >> 1;
    offA[m2] = l * 128 + ((((lr & 1) * 4 + kg) ^ (l & 7)) << 4);
  }
#pragma unroll
  for (int n2 = 0; n2 < 4; ++n2) {
    int lc = wc * 64 + n2 * 16 + fr;
    int l = lc >> 1;
    offB[n2] = 8192 + l * 128 + ((((lc & 1) * 4 + kg) ^ (l & 7)) << 4);
  }

  f32x4 acc[4][4];
  const f32x4 zero = {0.f, 0.f, 0.f, 0.f};
#pragma unroll
  for (int m = 0; m < 4; ++m)
#pragma unroll
    for (int n = 0; n < 4; ++n) acc[m][n] = zero;

  STAGE_TILE(0, 0);
  __syncthreads();

#pragma unroll 1
  for (int kt = 0; kt < 16; ++kt) {          // 16 K-tiles of 128 elems
    const int buf = kt & 1;
    const int ktn = (kt < 15) ? kt + 1 : 15; // last iter: junk re-stage, never read
    STAGE_TILE(buf ^ 1, ktn);                // overlaps this tile's compute
    const unsigned char* lb = lds + buf * 16384;
    i32x8 afr[4], bfr[4];
#pragma unroll
    for (int m2 = 0; m2 < 4; ++m2) {
      i32x4 v_ = *reinterpret_cast<const i32x4*>(lb + offA[m2]);
      afr[m2][0] = v_[0]; afr[m2][1] = v_[1]; afr[m2][2] = v_[2]; afr[m2][3] = v_[3];
      afr[m2][4] = 0; afr[m2][5] = 0; afr[m2][6] = 0; afr[m2][7] = 0;
    }
#pragma unroll
    for (int n2 = 0; n2 < 4; ++n2) {
      i32x4 v_ = *reinterpret_cast<const i32x4*>(lb + offB[n2]);
      bfr[n2][0] = v_[0]; bfr[n2][1] = v_[1]; bfr[n2][2] = v_[2]; bfr[n2][3] = v_[3];
      bfr[n2][4] = 0; bfr[n2][5] = 0; bfr[n2][6] = 0; bfr[n2][7] = 0;
    }
    __builtin_amdgcn_s_setprio(1);
#pragma unroll
    for (int m2 = 0; m2 < 4; ++m2)
#pragma unroll
      for (int n2 = 0; n2 < 4; ++n2)
        acc[m2][n2] = __builtin_amdgcn_mfma_scale_f32_16x16x128_f8f6f4(
            afr[m2], bfr[n2], acc[m2][n2], 4, 4, 0, 127, 0, 127);  // fmt 4 = FP4
    __builtin_amdgcn_s_setprio(0);
    __syncthreads();   // publishes buf^1 + protects buf re-stage next iter
  }

  __syncthreads();

  // C/D layout: col-in-frag = fr, row-in-frag = kg*4 + j (shape-determined)
  // global row = rowBase + wr*64 + m*16 + kg*4 + j
  // global col = colBase + wc*64 + n*16 + fr
  if (isMain) {
    float* shPhi = reinterpret_cast<float*>(lds);
    if (tid < 128) shPhi[tid] = dotv[rowBase + tid] - BETA_F;
    __syncthreads();
#pragma unroll
    for (int m = 0; m < 4; ++m) {
#pragma unroll
      for (int j = 0; j < 4; ++j) {
        int rl = wr * 64 + m * 16 + kg * 4 + j;
        float ph = shPhi[rl];
        float s1 = 0.f, ee = 0.f, ct = 0.f;
#pragma unroll
        for (int n = 0; n < 4; ++n) {
          int gcol = colBase + wc * 64 + n * 16 + fr;
          float c = acc[m][n][j] * INVQ;
          c = fminf(fmaxf(c, -1.f), 1.f);
          if (gcol < NCLS) {
            s1 += c;
            ee += __expf(ALPHA_F * c);
            ct += (c > ph) ? 1.f : 0.f;
          }
        }
#pragma unroll
        for (int o = 1; o < 16; o <<= 1) {
          s1 += __shfl_xor(s1, o);
          ee += __shfl_xor(ee, o);
          ct += __shfl_xor(ct, o);
        }
        if (fr == 0) {
          int grow = rowBase + rl;
          atomicAdd(&S1[grow], s1);
          atomicAdd(&Eacc[grow], ee);
          atomicAdd(&CNT[grow], ct);
        }
      }
    }
  } else {
    const float wgt = (rowTile == colTile) ? 1.f : 2.f;  // symmetry: off-diag x2
    int* shT = reinterpret_cast<int*>(lds);
    float* redbuf = reinterpret_cast<float*>(lds + 4096);
    if (tid < 128) shT[tid] = tgt[rowBase + tid];
    else if (tid < 256) shT[tid] = tgt[colBase + (tid - 128)];
    __syncthreads();
    float ps = 0.f, als = 0.f, pc = 0.f;
#pragma unroll
    for (int m = 0; m < 4; ++m) {
#pragma unroll
      for (int j = 0; j < 4; ++j) {
        int rl = wr * 64 + m * 16 + kg * 4 + j;
        int tr = shT[rl];
#pragma unroll
        for (int n = 0; n < 4; ++n) {
          int cl = wc * 64 + n * 16 + fr;
          float c = acc[m][n][j] * INVQ;   // sim is NOT clipped in the reference
          als += c;
          if (tr == shT[128 + cl]) { ps += c; pc += 1.f; }
        }
      }
    }
#pragma unroll
    for (int o = 1; o < 64; o <<= 1) {
      ps  += __shfl_xor(ps, o);
      als += __shfl_xor(als, o);
      pc  += __shfl_xor(pc, o);
    }
    if (lane == 0) {
      redbuf[wid * 3 + 0] = ps;
      redbuf[wid * 3 + 1] = als;
      redbuf[wid * 3 + 2] = pc;
    }
    __syncthreads();
    if (tid == 0) {
      float p = 0.f, a = 0.f, c2 = 0.f;
      for (int w = 0; w < 4; ++w) {
        p += redbuf[w * 3 + 0];
        a += redbuf[w * 3 + 1];
        c2 += redbuf[w * 3 + 2];
      }
      atomicAdd(&simAcc[0], wgt * p);
      atomicAdd(&simAcc[1], wgt * a);
      atomicAdd(&simAcc[2], wgt * c2);
    }
  }
}

__global__ void finalize_kernel(const float* __restrict__ dotv, const float* __restrict__ S1,
                                const float* __restrict__ Eacc, const float* __restrict__ CNT,
                                const float* __restrict__ simAcc, float* __restrict__ out) {
  __shared__ float sh[5][256];
  int tid = threadIdx.x;
  float sum_posc = 0.f, sum_s1 = 0.f, loss_sum = 0.f, mask_cnt = 0.f, correct = 0.f;
  for (int i = tid; i < NROWS; i += 256) {
    float d = dotv[i];
    float posc = fminf(fmaxf(d, -1.f), 1.f);   // pos_cos (clipped target cos)
    float phi = d - BETA_F;
    sum_posc += posc;
    sum_s1 += S1[i];
    float e = Eacc[i] - __expf(ALPHA_F * posc);   // exclude target column
    float cexcl = CNT[i] - 1.f;                   // target always counted (margin = BETA)
    float per = -phi + __logf(e) / ALPHA_F;
    if (cexcl > 0.5f) { loss_sum += per; mask_cnt += 1.f; }
    else correct += 1.f;                          // pred == target iff no non-target col > phi
  }
  sh[0][tid] = sum_posc; sh[1][tid] = sum_s1; sh[2][tid] = loss_sum;
  sh[3][tid] = mask_cnt; sh[4][tid] = correct;
  __syncthreads();
  for (int s = 128; s > 0; s >>= 1) {
    if (tid < s)
      for (int q = 0; q < 5; ++q) sh[q][tid] += sh[q][tid + s];
    __syncthreads();
  }
  if (tid == 0) {
    float posS = sh[0][0], s1S = sh[1][0], lossS = sh[2][0], maskS = sh[3][0], corr = sh[4][0];
    out[0] = lossS / fmaxf(maskS, 1.f);
    out[1] = corr / (float)NROWS;
    out[2] = posS / (float)NROWS;
    out[3] = (s1S - posS) / ((float)NROWS * (float)(NCLS - 1));
    float pos = simAcc[0], all = simAcc[1], pcnt = simAcc[2];
    out[4] = pos / pcnt;
    out[5] = (all - pos) / ((float)NROWS * (float)NROWS - pcnt);
  }
}

extern "C" void kernel_launch(void* const* d_in, const int* in_sizes, int n_in,
                              void* d_out, int out_size, void* d_ws, size_t ws_size,
                              hipStream_t stream) {
  const float* X  = (const float*)d_in[0];   // inputs  [4096][2048] f32
  const int*   tg = (const int*)d_in[1];     // targets [4096] i32
  const float* Kn = (const float*)d_in[2];   // kernel  [10000][2048] f32
  float* out = (float*)d_out;

  char* w = (char*)d_ws;
  unsigned char* f4A = (unsigned char*)w;                  // 4096*1024 B fp4
  unsigned char* f4B = f4A + (size_t)NROWS * DIMB;         // 10000*1024 B fp4
  float* dotv   = (float*)(w + (size_t)NROWS * DIMB + (size_t)NCLS * DIMB);
  float* S1     = dotv + NROWS;
  float* Eacc   = S1 + NROWS;
  float* CNT    = Eacc + NROWS;
  float* simAcc = CNT + NROWS;

  hipMemsetAsync(S1, 0, (3 * NROWS + 4) * sizeof(float), stream);

  const int nA8 = NROWS * DIM / 8, nT8 = nA8 + NCLS * DIM / 8;
  cast_fp4_kernel<<<2048, 256, 0, stream>>>(X, Kn, (unsigned int*)f4A,
                                            (unsigned int*)f4B, nA8, nT8);
  gather_dot_kernel<<<NROWS / 4, 256, 0, stream>>>(X, Kn, tg, dotv);

  // merged: 2560 main blocks (80x32, cols clamped+masked past 10000)
  //       +  528 sim triangle blocks (off-diag weighted x2)
  gemm_kernel<<<NMAIN_BLK + NSIM_BLK, 256, 0, stream>>>(
      f4A, f4B, dotv, tg, S1, Eacc, CNT, simAcc);

  finalize_kernel<<<1, 256, 0, stream>>>(dotv, S1, Eacc, CNT, simAcc, out);
}

// Round 12
// 149.212 us; speedup vs baseline: 2.0592x; 2.0592x over previous
//
#include <hip/hip_runtime.h>
#include <hip/hip_bf16.h>

#define NROWS 4096
#define NCLS  10000
#define DIM   2048
#define DIMB  1024          // bytes per row in fp4
#define ALPHA_F 10.0f
#define BETA_F  2.0f
#define FP4_SCALE 64.0f
#define INVQ (1.0f / (FP4_SCALE * FP4_SCALE))   // undo scale^2 on dot products
#define NMAIN_BLK 2560      // 80 col-tiles x 32 row-tiles
#define NSIM_BLK  528       // 32*33/2 triangle

typedef float f32x4 __attribute__((ext_vector_type(4)));
typedef int   i32x4 __attribute__((ext_vector_type(4)));
typedef int   i32x8 __attribute__((ext_vector_type(8)));

// f32 -> fp4 e2m1 RNE (code 0..7 = {0,0.5,1,1.5,2,3,4,6}, bit3 = sign),
// pre-scaled by FP4_SCALE, 8 elems -> 1 u32 of nibbles. X and Kn in one launch.
__global__ void cast_fp4_kernel(const float* __restrict__ X, const float* __restrict__ Kn,
                                unsigned int* __restrict__ dA, unsigned int* __restrict__ dB,
                                int nA8, int nT8) {
  int stride = gridDim.x * blockDim.x;
  for (int i = blockIdx.x * blockDim.x + threadIdx.x; i < nT8; i += stride) {
    const float* src; unsigned int* dst; int j;
    if (i < nA8) { src = X; dst = dA; j = i; } else { src = Kn; dst = dB; j = i - nA8; }
    float4 a = reinterpret_cast<const float4*>(src)[2 * j];
    float4 b = reinterpret_cast<const float4*>(src)[2 * j + 1];
    float v[8] = {a.x, a.y, a.z, a.w, b.x, b.y, b.z, b.w};
    unsigned int w = 0;
#pragma unroll
    for (int q = 0; q < 8; ++q) {
      float s = v[q] * FP4_SCALE;
      float av = fabsf(s);
      unsigned int code = (unsigned)(av > 0.25f) + (av > 0.75f) + (av > 1.25f)
                        + (av > 1.75f) + (av > 2.5f) + (av > 3.5f) + (av > 5.0f);
      code |= (s < 0.f) ? 8u : 0u;
      w |= code << (4 * q);
    }
    dst[j] = w;
  }
}

// fp32 dot(inputs_i, kernel[targets_i]) -> dotv[i]; one wave per row. Exact path.
__global__ void gather_dot_kernel(const float* __restrict__ X, const float* __restrict__ Kn,
                                  const int* __restrict__ tgt, float* __restrict__ dotv) {
  int gtid = blockIdx.x * blockDim.x + threadIdx.x;
  int wave = gtid >> 6;
  int lane = threadIdx.x & 63;
  if (wave >= NROWS) return;
  const float* xr = X + (size_t)wave * DIM;
  const float* kr = Kn + (size_t)tgt[wave] * DIM;
  float s = 0.f;
#pragma unroll
  for (int it = 0; it < DIM / 256; ++it) {
    int k = lane * 4 + it * 256;
    float4 a = *reinterpret_cast<const float4*>(xr + k);
    float4 b = *reinterpret_cast<const float4*>(kr + k);
    s += a.x * b.x + a.y * b.y + a.z * b.z + a.w * b.w;
  }
#pragma unroll
  for (int off = 32; off > 0; off >>= 1) s += __shfl_down(s, off);
  if (lane == 0) dotv[wave] = s;
}

// ---------------------------------------------------------------------------
// Merged 128x128 MX-fp4 (e2m1, unit scales) K=128 MFMA A*B^T with fused
// reduction epilogues; ONE dispatch covers the n x C GEMM (blocks < 2560)
// and the lower-triangle sim GEMM (blocks >= 2560).
// 256 threads = 4 waves (2x2, 64x64 each), BK=128, dbuf 16KB tiles ->
// 32KB LDS. __launch_bounds__(256,4): 4 blocks/CU = 128KB LDS, and the
// unified VGPR+AGPR budget (512/4 = 128/lane) EXACTLY fits acc(64 AGPR) +
// ~60 VGPR. (256,5) spilled acc to scratch: WRITE_SIZE 530MB, 3x slower.
// LDS geometry (measured zero-conflict, r11): row pairs packed into 128B
// lines; line l holds rows {2l,2l+1}; phys 16B slot8 = logical8 ^ (l&7),
// logical8 = (row&1)*4 + col16. Inverse pre-applied on gload SOURCE;
// dest linear (rule 21). Staging addresses fully hoisted (kt-invariant).
// ---------------------------------------------------------------------------

#define AS1 const __attribute__((address_space(1))) void*
#define AS3 __attribute__((address_space(3))) void*

__global__ __launch_bounds__(256, 4)
void gemm_kernel(const unsigned char* __restrict__ A,
                 const unsigned char* __restrict__ Bm,
                 const float* __restrict__ dotv,
                 const int* __restrict__ tgt,
                 float* __restrict__ S1, float* __restrict__ Eacc,
                 float* __restrict__ CNT, float* __restrict__ simAcc) {
  __shared__ unsigned char lds[2 * 16384];   // 2 bufs x (A 8KB + B 8KB)

  const int tid  = threadIdx.x;
  const int lane = tid & 63;
  const int wid  = tid >> 6;
  const int wr   = wid >> 1;       // 0..1
  const int wc   = wid & 1;        // 0..1
  const int fr   = lane & 15;
  const int kg   = lane >> 4;      // K-block 0..3 (32 elems = 16B) within K=128

  // block role + XCD-aware swizzle (both sub-grids are multiples of 8)
  const int lin = blockIdx.x;
  const bool isMain = lin < NMAIN_BLK;
  int rowTile, colTile, nB;
  const unsigned char* B;
  if (isMain) {
    int swz = (lin & 7) * 320 + (lin >> 3);  // cpx=320; col-major chunks
    colTile = swz / 32;                      // 10 col-panels per XCD
    rowTile = swz % 32;
    B = Bm; nB = NCLS;
  } else {
    int l2 = lin - NMAIN_BLK;
    int swz = (l2 & 7) * 66 + (l2 >> 3);     // cpx=66; triangle
    int r = 0;
    while ((r + 1) * (r + 2) / 2 <= swz) ++r;
    rowTile = r;
    colTile = swz - r * (r + 1) / 2;
    B = A; nB = NROWS;
  }
  const int rowBase = rowTile * 128;
  const int colBase = colTile * 128;

  // ---- staging precompute (kt-invariant) ----
  const int l0  = tid >> 3;                  // line within 32-line quarter
  const int sp  = tid & 7;                   // phys slot
  const int lg8 = sp ^ (l0 & 7);             // logical slot
  const int shi = lg8 >> 2, sc16 = lg8 & 3;
  const int rA0 = rowBase + 2 * l0 + shi;            // A never clamps
  const int rA1 = rA0 + 64;
  int cB0 = colBase + 2 * l0 + shi;      if (cB0 > nB - 1) cB0 = nB - 1;
  int cB1 = colBase + 64 + 2 * l0 + shi; if (cB1 > nB - 1) cB1 = nB - 1;
  const unsigned char* pA0 = A + (size_t)rA0 * DIMB + sc16 * 16;
  const unsigned char* pA1 = A + (size_t)rA1 * DIMB + sc16 * 16;
  const unsigned char* pB0 = B + (size_t)cB0 * DIMB + sc16 * 16;
  const unsigned char* pB1 = B + (size_t)cB1 * DIMB + sc16 * 16;
  const int dOff = l0 * 128 + sp * 16;       // linear LDS dest (quarter base added)

#define STAGE_TILE(BUF, KT)                                                     \
  { int ko_ = (KT) * 64;                                                        \
    unsigned char* d_ = lds + (BUF) * 16384 + dOff;                             \
    __builtin_amdgcn_global_load_lds((AS1)(pA0 + ko_), (AS3)(d_),          16, 0, 0); \
    __builtin_amdgcn_global_load_lds((AS1)(pA1 + ko_), (AS3)(d_ + 4096),   16, 0, 0); \
    __builtin_amdgcn_global_load_lds((AS1)(pB0 + ko_), (AS3)(d_ + 8192),   16, 0, 0); \
    __builtin_amdgcn_global_load_lds((AS1)(pB1 + ko_), (AS3)(d_ + 12288),  16, 0, 0); }

  // ---- fragment-read offsets (kt-invariant, fully unrolled -> registers) ----
  int offA[4], offB[4];
#pragma unroll
  for (int m2 = 0; m2 < 4; ++m2) {
    int lr = wr * 64 + m2 * 16 + fr;
    int l = lr >> 1;
    offA[m2] = l * 128 + ((((lr & 1) * 4 + kg) ^ (l & 7)) << 4);
  }
#pragma unroll
  for (int n2 = 0; n2 < 4; ++n2) {
    int lc = wc * 64 + n2 * 16 + fr;
    int l = lc >> 1;
    offB[n2] = 8192 + l * 128 + ((((lc & 1) * 4 + kg) ^ (l & 7)) << 4);
  }

  f32x4 acc[4][4];
  const f32x4 zero = {0.f, 0.f, 0.f, 0.f};
#pragma unroll
  for (int m = 0; m < 4; ++m)
#pragma unroll
    for (int n = 0; n < 4; ++n) acc[m][n] = zero;

  STAGE_TILE(0, 0);
  __syncthreads();

#pragma unroll 1
  for (int kt = 0; kt < 16; ++kt) {          // 16 K-tiles of 128 elems
    const int buf = kt & 1;
    const int ktn = (kt < 15) ? kt + 1 : 15; // last iter: junk re-stage, never read
    STAGE_TILE(buf ^ 1, ktn);                // overlaps this tile's compute
    const unsigned char* lb = lds + buf * 16384;
    i32x8 afr[4], bfr[4];
#pragma unroll
    for (int m2 = 0; m2 < 4; ++m2) {
      i32x4 v_ = *reinterpret_cast<const i32x4*>(lb + offA[m2]);
      afr[m2][0] = v_[0]; afr[m2][1] = v_[1]; afr[m2][2] = v_[2]; afr[m2][3] = v_[3];
      afr[m2][4] = 0; afr[m2][5] = 0; afr[m2][6] = 0; afr[m2][7] = 0;
    }
#pragma unroll
    for (int n2 = 0; n2 < 4; ++n2) {
      i32x4 v_ = *reinterpret_cast<const i32x4*>(lb + offB[n2]);
      bfr[n2][0] = v_[0]; bfr[n2][1] = v_[1]; bfr[n2][2] = v_[2]; bfr[n2][3] = v_[3];
      bfr[n2][4] = 0; bfr[n2][5] = 0; bfr[n2][6] = 0; bfr[n2][7] = 0;
    }
    __builtin_amdgcn_s_setprio(1);
#pragma unroll
    for (int m2 = 0; m2 < 4; ++m2)
#pragma unroll
      for (int n2 = 0; n2 < 4; ++n2)
        acc[m2][n2] = __builtin_amdgcn_mfma_scale_f32_16x16x128_f8f6f4(
            afr[m2], bfr[n2], acc[m2][n2], 4, 4, 0, 127, 0, 127);  // fmt 4 = FP4
    __builtin_amdgcn_s_setprio(0);
    __syncthreads();   // publishes buf^1 + protects buf re-stage next iter
  }

  __syncthreads();

  // C/D layout: col-in-frag = fr, row-in-frag = kg*4 + j (shape-determined)
  // global row = rowBase + wr*64 + m*16 + kg*4 + j
  // global col = colBase + wc*64 + n*16 + fr
  if (isMain) {
    float* shPhi = reinterpret_cast<float*>(lds);
    if (tid < 128) shPhi[tid] = dotv[rowBase + tid] - BETA_F;
    __syncthreads();
#pragma unroll
    for (int m = 0; m < 4; ++m) {
#pragma unroll
      for (int j = 0; j < 4; ++j) {
        int rl = wr * 64 + m * 16 + kg * 4 + j;
        float ph = shPhi[rl];
        float s1 = 0.f, ee = 0.f, ct = 0.f;
#pragma unroll
        for (int n = 0; n < 4; ++n) {
          int gcol = colBase + wc * 64 + n * 16 + fr;
          float c = acc[m][n][j] * INVQ;
          c = fminf(fmaxf(c, -1.f), 1.f);
          if (gcol < NCLS) {
            s1 += c;
            ee += __expf(ALPHA_F * c);
            ct += (c > ph) ? 1.f : 0.f;
          }
        }
#pragma unroll
        for (int o = 1; o < 16; o <<= 1) {
          s1 += __shfl_xor(s1, o);
          ee += __shfl_xor(ee, o);
          ct += __shfl_xor(ct, o);
        }
        if (fr == 0) {
          int grow = rowBase + rl;
          atomicAdd(&S1[grow], s1);
          atomicAdd(&Eacc[grow], ee);
          atomicAdd(&CNT[grow], ct);
        }
      }
    }
  } else {
    const float wgt = (rowTile == colTile) ? 1.f : 2.f;  // symmetry: off-diag x2
    int* shT = reinterpret_cast<int*>(lds);
    float* redbuf = reinterpret_cast<float*>(lds + 4096);
    if (tid < 128) shT[tid] = tgt[rowBase + tid];
    else if (tid < 256) shT[tid] = tgt[colBase + (tid - 128)];
    __syncthreads();
    float ps = 0.f, als = 0.f, pc = 0.f;
#pragma unroll
    for (int m = 0; m < 4; ++m) {
#pragma unroll
      for (int j = 0; j < 4; ++j) {
        int rl = wr * 64 + m * 16 + kg * 4 + j;
        int tr = shT[rl];
#pragma unroll
        for (int n = 0; n < 4; ++n) {
          int cl = wc * 64 + n * 16 + fr;
          float c = acc[m][n][j] * INVQ;   // sim is NOT clipped in the reference
          als += c;
          if (tr == shT[128 + cl]) { ps += c; pc += 1.f; }
        }
      }
    }
#pragma unroll
    for (int o = 1; o < 64; o <<= 1) {
      ps  += __shfl_xor(ps, o);
      als += __shfl_xor(als, o);
      pc  += __shfl_xor(pc, o);
    }
    if (lane == 0) {
      redbuf[wid * 3 + 0] = ps;
      redbuf[wid * 3 + 1] = als;
      redbuf[wid * 3 + 2] = pc;
    }
    __syncthreads();
    if (tid == 0) {
      float p = 0.f, a = 0.f, c2 = 0.f;
      for (int w = 0; w < 4; ++w) {
        p += redbuf[w * 3 + 0];
        a += redbuf[w * 3 + 1];
        c2 += redbuf[w * 3 + 2];
      }
      atomicAdd(&simAcc[0], wgt * p);
      atomicAdd(&simAcc[1], wgt * a);
      atomicAdd(&simAcc[2], wgt * c2);
    }
  }
}

__global__ void finalize_kernel(const float* __restrict__ dotv, const float* __restrict__ S1,
                                const float* __restrict__ Eacc, const float* __restrict__ CNT,
                                const float* __restrict__ simAcc, float* __restrict__ out) {
  __shared__ float sh[5][256];
  int tid = threadIdx.x;
  float sum_posc = 0.f, sum_s1 = 0.f, loss_sum = 0.f, mask_cnt = 0.f, correct = 0.f;
  for (int i = tid; i < NROWS; i += 256) {
    float d = dotv[i];
    float posc = fminf(fmaxf(d, -1.f), 1.f);   // pos_cos (clipped target cos)
    float phi = d - BETA_F;
    sum_posc += posc;
    sum_s1 += S1[i];
    float e = Eacc[i] - __expf(ALPHA_F * posc);   // exclude target column
    float cexcl = CNT[i] - 1.f;                   // target always counted (margin = BETA)
    float per = -phi + __logf(e) / ALPHA_F;
    if (cexcl > 0.5f) { loss_sum += per; mask_cnt += 1.f; }
    else correct += 1.f;                          // pred == target iff no non-target col > phi
  }
  sh[0][tid] = sum_posc; sh[1][tid] = sum_s1; sh[2][tid] = loss_sum;
  sh[3][tid] = mask_cnt; sh[4][tid] = correct;
  __syncthreads();
  for (int s = 128; s > 0; s >>= 1) {
    if (tid < s)
      for (int q = 0; q < 5; ++q) sh[q][tid] += sh[q][tid + s];
    __syncthreads();
  }
  if (tid == 0) {
    float posS = sh[0][0], s1S = sh[1][0], lossS = sh[2][0], maskS = sh[3][0], corr = sh[4][0];
    out[0] = lossS / fmaxf(maskS, 1.f);
    out[1] = corr / (float)NROWS;
    out[2] = posS / (float)NROWS;
    out[3] = (s1S - posS) / ((float)NROWS * (float)(NCLS - 1));
    float pos = simAcc[0], all = simAcc[1], pcnt = simAcc[2];
    out[4] = pos / pcnt;
    out[5] = (all - pos) / ((float)NROWS * (float)NROWS - pcnt);
  }
}

extern "C" void kernel_launch(void* const* d_in, const int* in_sizes, int n_in,
                              void* d_out, int out_size, void* d_ws, size_t ws_size,
                              hipStream_t stream) {
  const float* X  = (const float*)d_in[0];   // inputs  [4096][2048] f32
  const int*   tg = (const int*)d_in[1];     // targets [4096] i32
  const float* Kn = (const float*)d_in[2];   // kernel  [10000][2048] f32
  float* out = (float*)d_out;

  char* w = (char*)d_ws;
  unsigned char* f4A = (unsigned char*)w;                  // 4096*1024 B fp4
  unsigned char* f4B = f4A + (size_t)NROWS * DIMB;         // 10000*1024 B fp4
  float* dotv   = (float*)(w + (size_t)NROWS * DIMB + (size_t)NCLS * DIMB);
  float* S1     = dotv + NROWS;
  float* Eacc   = S1 + NROWS;
  float* CNT    = Eacc + NROWS;
  float* simAcc = CNT + NROWS;

  hipMemsetAsync(S1, 0, (3 * NROWS + 4) * sizeof(float), stream);

  const int nA8 = NROWS * DIM / 8, nT8 = nA8 + NCLS * DIM / 8;
  cast_fp4_kernel<<<2048, 256, 0, stream>>>(X, Kn, (unsigned int*)f4A,
                                            (unsigned int*)f4B, nA8, nT8);
  gather_dot_kernel<<<NROWS / 4, 256, 0, stream>>>(X, Kn, tg, dotv);

  // merged: 2560 main blocks (80x32, cols clamped+masked past 10000)
  //       +  528 sim triangle blocks (off-diag weighted x2)
  gemm_kernel<<<NMAIN_BLK + NSIM_BLK, 256, 0, stream>>>(
      f4A, f4B, dotv, tg, S1, Eacc, CNT, simAcc);

  finalize_kernel<<<1, 256, 0, stream>>>(dotv, S1, Eacc, CNT, simAcc, out);
}

// Round 13
// 147.300 us; speedup vs baseline: 2.0859x; 1.0130x over previous
//
#include <hip/hip_runtime.h>
#include <hip/hip_bf16.h>

#define NROWS 4096
#define NCLS  10000
#define DIM   2048
#define DIMB  1024          // bytes per row in fp4
#define ALPHA_F 10.0f
#define BETA_F  2.0f
#define FP4_SCALE 64.0f
#define INVQ (1.0f / (FP4_SCALE * FP4_SCALE))   // undo scale^2 on dot products
#define NMAIN_BLK 2560      // 80 col-tiles x 32 row-tiles
#define NSIM_BLK  528       // 32*33/2 triangle

typedef float f32x4 __attribute__((ext_vector_type(4)));
typedef int   i32x4 __attribute__((ext_vector_type(4)));
typedef int   i32x8 __attribute__((ext_vector_type(8)));

// Merged prep: blocks [0,2048) cast f32 -> fp4 e2m1 (pre-scaled by FP4_SCALE);
// blocks [2048,3072) compute exact fp32 dot(inputs_i, kernel[tgt_i]) (1 wave/row).
__global__ void prep_kernel(const float* __restrict__ X, const float* __restrict__ Kn,
                            const int* __restrict__ tgt,
                            unsigned int* __restrict__ dA, unsigned int* __restrict__ dB,
                            float* __restrict__ dotv, int nA8, int nT8) {
  if (blockIdx.x < 2048) {
    int stride = 2048 * blockDim.x;
    for (int i = blockIdx.x * blockDim.x + threadIdx.x; i < nT8; i += stride) {
      const float* src; unsigned int* dst; int j;
      if (i < nA8) { src = X; dst = dA; j = i; } else { src = Kn; dst = dB; j = i - nA8; }
      float4 a = reinterpret_cast<const float4*>(src)[2 * j];
      float4 b = reinterpret_cast<const float4*>(src)[2 * j + 1];
      float v[8] = {a.x, a.y, a.z, a.w, b.x, b.y, b.z, b.w};
      unsigned int w = 0;
#pragma unroll
      for (int q = 0; q < 8; ++q) {
        float s = v[q] * FP4_SCALE;
        float av = fabsf(s);
        unsigned int code = (unsigned)(av > 0.25f) + (av > 0.75f) + (av > 1.25f)
                          + (av > 1.75f) + (av > 2.5f) + (av > 3.5f) + (av > 5.0f);
        code |= (s < 0.f) ? 8u : 0u;
        w |= code << (4 * q);
      }
      dst[j] = w;
    }
  } else {
    int gtid = (blockIdx.x - 2048) * blockDim.x + threadIdx.x;
    int wave = gtid >> 6;
    int lane = threadIdx.x & 63;
    if (wave >= NROWS) return;
    const float* xr = X + (size_t)wave * DIM;
    const float* kr = Kn + (size_t)tgt[wave] * DIM;
    float s = 0.f;
#pragma unroll
    for (int it = 0; it < DIM / 256; ++it) {
      int k = lane * 4 + it * 256;
      float4 a = *reinterpret_cast<const float4*>(xr + k);
      float4 b = *reinterpret_cast<const float4*>(kr + k);
      s += a.x * b.x + a.y * b.y + a.z * b.z + a.w * b.w;
    }
#pragma unroll
    for (int off = 32; off > 0; off >>= 1) s += __shfl_down(s, off);
    if (lane == 0) dotv[wave] = s;
  }
}

// ---------------------------------------------------------------------------
// Merged 128x128 MX-fp4 (e2m1, unit scales) K=128 MFMA A*B^T with fused
// reduction epilogues; ONE dispatch covers the n x C GEMM (blocks < 2560)
// and the lower-triangle sim GEMM (blocks >= 2560).
// 256 threads = 4 waves (2x2, 64x64 each), BK=128. TRIPLE-buffered 16KB
// tiles (48KB LDS, 3 blocks/CU): iter t stages tile t+2 -> buf (t+2)%3, so
// every global_load_lds ages TWO iterations before the barrier that
// publishes it (hides HBM-miss latency that the 2-buffer vmcnt(0) loop
// exposed). Gate = counted s_waitcnt vmcnt(4) (in-order retire: waits for
// tile t+1's 4 loads exactly, leaves t+2's 4 in flight) + raw s_barrier.
// Hazards: stage@t writes buf (t-1)%3 whose ds_reads completed before the
// t-1 barrier; reads@t+1 published by end-of-t vmcnt(4)+barrier. ds_read ->
// MFMA ordering via compiler data-dep lgkm waits (plain C++ loads).
// (256,3): reg budget 170/lane, no spill (r11 lesson: (256,5) spilled acc).
// LDS zero-conflict geometry and hoisted staging addresses as r12.
// ---------------------------------------------------------------------------

#define AS1 const __attribute__((address_space(1))) void*
#define AS3 __attribute__((address_space(3))) void*

__global__ __launch_bounds__(256, 3)
void gemm_kernel(const unsigned char* __restrict__ A,
                 const unsigned char* __restrict__ Bm,
                 const float* __restrict__ dotv,
                 const int* __restrict__ tgt,
                 float* __restrict__ S1, float* __restrict__ Eacc,
                 float* __restrict__ CNT, float* __restrict__ simAcc) {
  __shared__ unsigned char lds[3 * 16384];   // 3 bufs x (A 8KB + B 8KB)

  const int tid  = threadIdx.x;
  const int lane = tid & 63;
  const int wid  = tid >> 6;
  const int wr   = wid >> 1;       // 0..1
  const int wc   = wid & 1;        // 0..1
  const int fr   = lane & 15;
  const int kg   = lane >> 4;      // K-block 0..3 (32 elems = 16B) within K=128

  // block role + XCD-aware swizzle (both sub-grids are multiples of 8)
  const int lin = blockIdx.x;
  const bool isMain = lin < NMAIN_BLK;
  int rowTile, colTile, nB;
  const unsigned char* B;
  if (isMain) {
    int swz = (lin & 7) * 320 + (lin >> 3);  // cpx=320; col-major chunks
    colTile = swz / 32;                      // 10 col-panels per XCD
    rowTile = swz % 32;
    B = Bm; nB = NCLS;
  } else {
    int l2 = lin - NMAIN_BLK;
    int swz = (l2 & 7) * 66 + (l2 >> 3);     // cpx=66; triangle
    int r = 0;
    while ((r + 1) * (r + 2) / 2 <= swz) ++r;
    rowTile = r;
    colTile = swz - r * (r + 1) / 2;
    B = A; nB = NROWS;
  }
  const int rowBase = rowTile * 128;
  const int colBase = colTile * 128;

  // ---- staging precompute (kt-invariant) ----
  const int l0  = tid >> 3;                  // line within 32-line quarter
  const int sp  = tid & 7;                   // phys slot
  const int lg8 = sp ^ (l0 & 7);             // logical slot
  const int shi = lg8 >> 2, sc16 = lg8 & 3;
  const int rA0 = rowBase + 2 * l0 + shi;            // A never clamps
  const int rA1 = rA0 + 64;
  int cB0 = colBase + 2 * l0 + shi;      if (cB0 > nB - 1) cB0 = nB - 1;
  int cB1 = colBase + 64 + 2 * l0 + shi; if (cB1 > nB - 1) cB1 = nB - 1;
  const unsigned char* pA0 = A + (size_t)rA0 * DIMB + sc16 * 16;
  const unsigned char* pA1 = A + (size_t)rA1 * DIMB + sc16 * 16;
  const unsigned char* pB0 = B + (size_t)cB0 * DIMB + sc16 * 16;
  const unsigned char* pB1 = B + (size_t)cB1 * DIMB + sc16 * 16;
  const int dOff = l0 * 128 + sp * 16;       // linear LDS dest (quarter base added)

#define STAGE_TILE(BUF, KT)                                                     \
  { int ko_ = (KT) * 64;                                                        \
    unsigned char* d_ = lds + (BUF) * 16384 + dOff;                             \
    __builtin_amdgcn_global_load_lds((AS1)(pA0 + ko_), (AS3)(d_),          16, 0, 0); \
    __builtin_amdgcn_global_load_lds((AS1)(pA1 + ko_), (AS3)(d_ + 4096),   16, 0, 0); \
    __builtin_amdgcn_global_load_lds((AS1)(pB0 + ko_), (AS3)(d_ + 8192),   16, 0, 0); \
    __builtin_amdgcn_global_load_lds((AS1)(pB1 + ko_), (AS3)(d_ + 12288),  16, 0, 0); }

  // ---- fragment-read offsets (kt-invariant, fully unrolled -> registers) ----
  int offA[4], offB[4];
#pragma unroll
  for (int m2 = 0; m2 < 4; ++m2) {
    int lr = wr * 64 + m2 * 16 + fr;
    int l = lr >> 1;
    offA[m2] = l * 128 + ((((lr & 1) * 4 + kg) ^ (l & 7)) << 4);
  }
#pragma unroll
  for (int n2 = 0; n2 < 4; ++n2) {
    int lc = wc * 64 + n2 * 16 + fr;
    int l = lc >> 1;
    offB[n2] = 8192 + l * 128 + ((((lc & 1) * 4 + kg) ^ (l & 7)) << 4);
  }

  f32x4 acc[4][4];
  const f32x4 zero = {0.f, 0.f, 0.f, 0.f};
#pragma unroll
  for (int m = 0; m < 4; ++m)
#pragma unroll
    for (int n = 0; n < 4; ++n) acc[m][n] = zero;

  // prologue: tiles 0,1 -> bufs 0,1; wait tile0 (4 newest stay in flight)
  STAGE_TILE(0, 0);
  STAGE_TILE(1, 1);
  asm volatile("s_waitcnt vmcnt(4)" ::: "memory");
  asm volatile("s_barrier" ::: "memory");

#pragma unroll 1
  for (int kt = 0; kt < 16; ++kt) {          // 16 K-tiles of 128 elems
    const int buf = kt % 3;
    const int sbuf = (kt + 2) % 3;
    int ktn = kt + 2; if (ktn > 15) ktn = 15;  // tail: junk re-stage, never read
    STAGE_TILE(sbuf, ktn);                   // ages 2 iterations before use
    const unsigned char* lb = lds + buf * 16384;
    i32x8 afr[4], bfr[4];
#pragma unroll
    for (int m2 = 0; m2 < 4; ++m2) {
      i32x4 v_ = *reinterpret_cast<const i32x4*>(lb + offA[m2]);
      afr[m2][0] = v_[0]; afr[m2][1] = v_[1]; afr[m2][2] = v_[2]; afr[m2][3] = v_[3];
      afr[m2][4] = 0; afr[m2][5] = 0; afr[m2][6] = 0; afr[m2][7] = 0;
    }
#pragma unroll
    for (int n2 = 0; n2 < 4; ++n2) {
      i32x4 v_ = *reinterpret_cast<const i32x4*>(lb + offB[n2]);
      bfr[n2][0] = v_[0]; bfr[n2][1] = v_[1]; bfr[n2][2] = v_[2]; bfr[n2][3] = v_[3];
      bfr[n2][4] = 0; bfr[n2][5] = 0; bfr[n2][6] = 0; bfr[n2][7] = 0;
    }
    __builtin_amdgcn_s_setprio(1);
#pragma unroll
    for (int m2 = 0; m2 < 4; ++m2)
#pragma unroll
      for (int n2 = 0; n2 < 4; ++n2)
        acc[m2][n2] = __builtin_amdgcn_mfma_scale_f32_16x16x128_f8f6f4(
            afr[m2], bfr[n2], acc[m2][n2], 4, 4, 0, 127, 0, 127);  // fmt 4 = FP4
    __builtin_amdgcn_s_setprio(0);
    // counted gate: retire tile kt+1's 4 loads (oldest), keep kt+2's in flight
    asm volatile("s_waitcnt vmcnt(4)" ::: "memory");
    asm volatile("s_barrier" ::: "memory");
  }

  asm volatile("s_waitcnt vmcnt(0) lgkmcnt(0)" ::: "memory");
  __syncthreads();

  // C/D layout: col-in-frag = fr, row-in-frag = kg*4 + j (shape-determined)
  // global row = rowBase + wr*64 + m*16 + kg*4 + j
  // global col = colBase + wc*64 + n*16 + fr
  if (isMain) {
    float* shPhi = reinterpret_cast<float*>(lds);
    if (tid < 128) shPhi[tid] = dotv[rowBase + tid] - BETA_F;
    __syncthreads();
#pragma unroll
    for (int m = 0; m < 4; ++m) {
#pragma unroll
      for (int j = 0; j < 4; ++j) {
        int rl = wr * 64 + m * 16 + kg * 4 + j;
        float ph = shPhi[rl];
        float s1 = 0.f, ee = 0.f, ct = 0.f;
#pragma unroll
        for (int n = 0; n < 4; ++n) {
          int gcol = colBase + wc * 64 + n * 16 + fr;
          float c = acc[m][n][j] * INVQ;
          c = fminf(fmaxf(c, -1.f), 1.f);
          if (gcol < NCLS) {
            s1 += c;
            ee += __expf(ALPHA_F * c);
            ct += (c > ph) ? 1.f : 0.f;
          }
        }
#pragma unroll
        for (int o = 1; o < 16; o <<= 1) {
          s1 += __shfl_xor(s1, o);
          ee += __shfl_xor(ee, o);
          ct += __shfl_xor(ct, o);
        }
        if (fr == 0) {
          int grow = rowBase + rl;
          atomicAdd(&S1[grow], s1);
          atomicAdd(&Eacc[grow], ee);
          atomicAdd(&CNT[grow], ct);
        }
      }
    }
  } else {
    const float wgt = (rowTile == colTile) ? 1.f : 2.f;  // symmetry: off-diag x2
    int* shT = reinterpret_cast<int*>(lds);
    float* redbuf = reinterpret_cast<float*>(lds + 4096);
    if (tid < 128) shT[tid] = tgt[rowBase + tid];
    else if (tid < 256) shT[tid] = tgt[colBase + (tid - 128)];
    __syncthreads();
    float ps = 0.f, als = 0.f, pc = 0.f;
#pragma unroll
    for (int m = 0; m < 4; ++m) {
#pragma unroll
      for (int j = 0; j < 4; ++j) {
        int rl = wr * 64 + m * 16 + kg * 4 + j;
        int tr = shT[rl];
#pragma unroll
        for (int n = 0; n < 4; ++n) {
          int cl = wc * 64 + n * 16 + fr;
          float c = acc[m][n][j] * INVQ;   // sim is NOT clipped in the reference
          als += c;
          if (tr == shT[128 + cl]) { ps += c; pc += 1.f; }
        }
      }
    }
#pragma unroll
    for (int o = 1; o < 64; o <<= 1) {
      ps  += __shfl_xor(ps, o);
      als += __shfl_xor(als, o);
      pc  += __shfl_xor(pc, o);
    }
    if (lane == 0) {
      redbuf[wid * 3 + 0] = ps;
      redbuf[wid * 3 + 1] = als;
      redbuf[wid * 3 + 2] = pc;
    }
    __syncthreads();
    if (tid == 0) {
      float p = 0.f, a = 0.f, c2 = 0.f;
      for (int w = 0; w < 4; ++w) {
        p += redbuf[w * 3 + 0];
        a += redbuf[w * 3 + 1];
        c2 += redbuf[w * 3 + 2];
      }
      atomicAdd(&simAcc[0], wgt * p);
      atomicAdd(&simAcc[1], wgt * a);
      atomicAdd(&simAcc[2], wgt * c2);
    }
  }
}

__global__ void finalize_kernel(const float* __restrict__ dotv, const float* __restrict__ S1,
                                const float* __restrict__ Eacc, const float* __restrict__ CNT,
                                const float* __restrict__ simAcc, float* __restrict__ out) {
  __shared__ float sh[5][256];
  int tid = threadIdx.x;
  float sum_posc = 0.f, sum_s1 = 0.f, loss_sum = 0.f, mask_cnt = 0.f, correct = 0.f;
  for (int i = tid; i < NROWS; i += 256) {
    float d = dotv[i];
    float posc = fminf(fmaxf(d, -1.f), 1.f);   // pos_cos (clipped target cos)
    float phi = d - BETA_F;
    sum_posc += posc;
    sum_s1 += S1[i];
    float e = Eacc[i] - __expf(ALPHA_F * posc);   // exclude target column
    float cexcl = CNT[i] - 1.f;                   // target always counted (margin = BETA)
    float per = -phi + __logf(e) / ALPHA_F;
    if (cexcl > 0.5f) { loss_sum += per; mask_cnt += 1.f; }
    else correct += 1.f;                          // pred == target iff no non-target col > phi
  }
  sh[0][tid] = sum_posc; sh[1][tid] = sum_s1; sh[2][tid] = loss_sum;
  sh[3][tid] = mask_cnt; sh[4][tid] = correct;
  __syncthreads();
  for (int s = 128; s > 0; s >>= 1) {
    if (tid < s)
      for (int q = 0; q < 5; ++q) sh[q][tid] += sh[q][tid + s];
    __syncthreads();
  }
  if (tid == 0) {
    float posS = sh[0][0], s1S = sh[1][0], lossS = sh[2][0], maskS = sh[3][0], corr = sh[4][0];
    out[0] = lossS / fmaxf(maskS, 1.f);
    out[1] = corr / (float)NROWS;
    out[2] = posS / (float)NROWS;
    out[3] = (s1S - posS) / ((float)NROWS * (float)(NCLS - 1));
    float pos = simAcc[0], all = simAcc[1], pcnt = simAcc[2];
    out[4] = pos / pcnt;
    out[5] = (all - pos) / ((float)NROWS * (float)NROWS - pcnt);
  }
}

extern "C" void kernel_launch(void* const* d_in, const int* in_sizes, int n_in,
                              void* d_out, int out_size, void* d_ws, size_t ws_size,
                              hipStream_t stream) {
  const float* X  = (const float*)d_in[0];   // inputs  [4096][2048] f32
  const int*   tg = (const int*)d_in[1];     // targets [4096] i32
  const float* Kn = (const float*)d_in[2];   // kernel  [10000][2048] f32
  float* out = (float*)d_out;

  char* w = (char*)d_ws;
  unsigned char* f4A = (unsigned char*)w;                  // 4096*1024 B fp4
  unsigned char* f4B = f4A + (size_t)NROWS * DIMB;         // 10000*1024 B fp4
  float* dotv   = (float*)(w + (size_t)NROWS * DIMB + (size_t)NCLS * DIMB);
  float* S1     = dotv + NROWS;
  float* Eacc   = S1 + NROWS;
  float* CNT    = Eacc + NROWS;
  float* simAcc = CNT + NROWS;

  hipMemsetAsync(S1, 0, (3 * NROWS + 4) * sizeof(float), stream);

  const int nA8 = NROWS * DIM / 8, nT8 = nA8 + NCLS * DIM / 8;
  // merged prep: 2048 cast blocks + 1024 gather-dot blocks
  prep_kernel<<<3072, 256, 0, stream>>>(X, Kn, tg, (unsigned int*)f4A,
                                        (unsigned int*)f4B, dotv, nA8, nT8);

  // merged: 2560 main blocks (80x32, cols clamped+masked past 10000)
  //       +  528 sim triangle blocks (off-diag weighted x2)
  gemm_kernel<<<NMAIN_BLK + NSIM_BLK, 256, 0, stream>>>(
      f4A, f4B, dotv, tg, S1, Eacc, CNT, simAcc);

  finalize_kernel<<<1, 256, 0, stream>>>(dotv, S1, Eacc, CNT, simAcc, out);
}

// Round 14
// 134.891 us; speedup vs baseline: 2.2778x; 1.0920x over previous
//
#include <hip/hip_runtime.h>
#include <hip/hip_bf16.h>

#define NROWS 4096
#define NCLS  10000
#define DIM   2048
#define DIMB  1024          // bytes per row in fp4
#define ALPHA_F 10.0f
#define BETA_F  2.0f
#define FP4_SCALE 64.0f
#define INVQ (1.0f / (FP4_SCALE * FP4_SCALE))   // undo scale^2 on dot products
#define NMAIN_BLK 2528      // 79 col-tiles x 32 row-tiles (79*128=10112 >= 10000)
#define NSIM_BLK  528       // 32*33/2 triangle

typedef float f32x4 __attribute__((ext_vector_type(4)));
typedef int   i32x4 __attribute__((ext_vector_type(4)));
typedef int   i32x8 __attribute__((ext_vector_type(8)));

// Merged prep: blocks [0,2048) cast f32 -> fp4 e2m1 (pre-scaled by FP4_SCALE);
// blocks [2048,3072) compute exact fp32 dot(inputs_i, kernel[tgt_i]) (1 wave/row).
__global__ void prep_kernel(const float* __restrict__ X, const float* __restrict__ Kn,
                            const int* __restrict__ tgt,
                            unsigned int* __restrict__ dA, unsigned int* __restrict__ dB,
                            float* __restrict__ dotv, int nA8, int nT8) {
  if (blockIdx.x < 2048) {
    int stride = 2048 * blockDim.x;
    for (int i = blockIdx.x * blockDim.x + threadIdx.x; i < nT8; i += stride) {
      const float* src; unsigned int* dst; int j;
      if (i < nA8) { src = X; dst = dA; j = i; } else { src = Kn; dst = dB; j = i - nA8; }
      float4 a = reinterpret_cast<const float4*>(src)[2 * j];
      float4 b = reinterpret_cast<const float4*>(src)[2 * j + 1];
      float v[8] = {a.x, a.y, a.z, a.w, b.x, b.y, b.z, b.w};
      unsigned int w = 0;
#pragma unroll
      for (int q = 0; q < 8; ++q) {
        float s = v[q] * FP4_SCALE;
        float av = fabsf(s);
        unsigned int code = (unsigned)(av > 0.25f) + (av > 0.75f) + (av > 1.25f)
                          + (av > 1.75f) + (av > 2.5f) + (av > 3.5f) + (av > 5.0f);
        code |= (s < 0.f) ? 8u : 0u;
        w |= code << (4 * q);
      }
      dst[j] = w;
    }
  } else {
    int gtid = (blockIdx.x - 2048) * blockDim.x + threadIdx.x;
    int wave = gtid >> 6;
    int lane = threadIdx.x & 63;
    if (wave >= NROWS) return;
    const float* xr = X + (size_t)wave * DIM;
    const float* kr = Kn + (size_t)tgt[wave] * DIM;
    float s = 0.f;
#pragma unroll
    for (int it = 0; it < DIM / 256; ++it) {
      int k = lane * 4 + it * 256;
      float4 a = *reinterpret_cast<const float4*>(xr + k);
      float4 b = *reinterpret_cast<const float4*>(kr + k);
      s += a.x * b.x + a.y * b.y + a.z * b.z + a.w * b.w;
    }
#pragma unroll
    for (int off = 32; off > 0; off >>= 1) s += __shfl_down(s, off);
    if (lane == 0) dotv[wave] = s;
  }
}

// ---------------------------------------------------------------------------
// Merged 128x128 MX-fp4 (e2m1, unit scales) K=128 MFMA A*B^T with fused
// reduction epilogues; ONE dispatch: main n x C GEMM (blocks < 2528) +
// lower-triangle sim GEMM (blocks >= 2528). r12-proven K-loop: 256 threads =
// 4 waves (2x2, 64x64 each), BK=128, dbuf 16KB tiles -> 32KB LDS,
// __launch_bounds__(256,4) = 4 blocks/CU (128KB LDS; 128 reg/lane budget
// fits acc 64 AGPR + ~60 VGPR; (256,5) spilled, (256,3) lost TLP).
// Frag i32x8 tuples declared OUTSIDE the K-loop, zero-halves written once
// (fp4 uses v[0:3] only) -> no per-iter v_mov re-zeroing.
// Epilogue reduce packs ct (exact integer at x4096) with s1 -> 8 swizzles
// per (m,j) instead of 12; CNT recovered exactly via rintf, s1 quantization
// <=0.03/tile -> ~1e-6 on out[3] (threshold 5.8e-2).
// LDS zero-conflict geometry (r12-measured 0) + hoisted staging addresses.
// ---------------------------------------------------------------------------

#define AS1 const __attribute__((address_space(1))) void*
#define AS3 __attribute__((address_space(3))) void*

__global__ __launch_bounds__(256, 4)
void gemm_kernel(const unsigned char* __restrict__ A,
                 const unsigned char* __restrict__ Bm,
                 const float* __restrict__ dotv,
                 const int* __restrict__ tgt,
                 float* __restrict__ S1, float* __restrict__ Eacc,
                 float* __restrict__ CNT, float* __restrict__ simAcc) {
  __shared__ unsigned char lds[2 * 16384];   // 2 bufs x (A 8KB + B 8KB)

  const int tid  = threadIdx.x;
  const int lane = tid & 63;
  const int wid  = tid >> 6;
  const int wr   = wid >> 1;       // 0..1
  const int wc   = wid & 1;        // 0..1
  const int fr   = lane & 15;
  const int kg   = lane >> 4;      // K-block 0..3 (32 elems = 16B) within K=128

  // block role + XCD-aware swizzle (both sub-grids are multiples of 8)
  const int lin = blockIdx.x;
  const bool isMain = lin < NMAIN_BLK;
  int rowTile, colTile, nB;
  const unsigned char* B;
  if (isMain) {
    int swz = (lin & 7) * 316 + (lin >> 3);  // cpx=316; col-major chunks
    colTile = swz / 32;                      // ~10 col-panels per XCD
    rowTile = swz % 32;
    B = Bm; nB = NCLS;
  } else {
    int l2 = lin - NMAIN_BLK;
    int swz = (l2 & 7) * 66 + (l2 >> 3);     // cpx=66; triangle
    int r = 0;
    while ((r + 1) * (r + 2) / 2 <= swz) ++r;
    rowTile = r;
    colTile = swz - r * (r + 1) / 2;
    B = A; nB = NROWS;
  }
  const int rowBase = rowTile * 128;
  const int colBase = colTile * 128;

  // ---- staging precompute (kt-invariant) ----
  const int l0  = tid >> 3;                  // line within 32-line quarter
  const int sp  = tid & 7;                   // phys slot
  const int lg8 = sp ^ (l0 & 7);             // logical slot
  const int shi = lg8 >> 2, sc16 = lg8 & 3;
  const int rA0 = rowBase + 2 * l0 + shi;            // A never clamps
  const int rA1 = rA0 + 64;
  int cB0 = colBase + 2 * l0 + shi;      if (cB0 > nB - 1) cB0 = nB - 1;
  int cB1 = colBase + 64 + 2 * l0 + shi; if (cB1 > nB - 1) cB1 = nB - 1;
  const unsigned char* pA0 = A + (size_t)rA0 * DIMB + sc16 * 16;
  const unsigned char* pA1 = A + (size_t)rA1 * DIMB + sc16 * 16;
  const unsigned char* pB0 = B + (size_t)cB0 * DIMB + sc16 * 16;
  const unsigned char* pB1 = B + (size_t)cB1 * DIMB + sc16 * 16;
  const int dOff = l0 * 128 + sp * 16;       // linear LDS dest (quarter base added)

#define STAGE_TILE(BUF, KT)                                                     \
  { int ko_ = (KT) * 64;                                                        \
    unsigned char* d_ = lds + (BUF) * 16384 + dOff;                             \
    __builtin_amdgcn_global_load_lds((AS1)(pA0 + ko_), (AS3)(d_),          16, 0, 0); \
    __builtin_amdgcn_global_load_lds((AS1)(pA1 + ko_), (AS3)(d_ + 4096),   16, 0, 0); \
    __builtin_amdgcn_global_load_lds((AS1)(pB0 + ko_), (AS3)(d_ + 8192),   16, 0, 0); \
    __builtin_amdgcn_global_load_lds((AS1)(pB1 + ko_), (AS3)(d_ + 12288),  16, 0, 0); }

  // ---- fragment-read offsets (kt-invariant, fully unrolled -> registers) ----
  int offA[4], offB[4];
#pragma unroll
  for (int m2 = 0; m2 < 4; ++m2) {
    int lr = wr * 64 + m2 * 16 + fr;
    int l = lr >> 1;
    offA[m2] = l * 128 + ((((lr & 1) * 4 + kg) ^ (l & 7)) << 4);
  }
#pragma unroll
  for (int n2 = 0; n2 < 4; ++n2) {
    int lc = wc * 64 + n2 * 16 + fr;
    int l = lc >> 1;
    offB[n2] = 8192 + l * 128 + ((((lc & 1) * 4 + kg) ^ (l & 7)) << 4);
  }

  f32x4 acc[4][4];
  const f32x4 zero = {0.f, 0.f, 0.f, 0.f};
#pragma unroll
  for (int m = 0; m < 4; ++m)
#pragma unroll
    for (int n = 0; n < 4; ++n) acc[m][n] = zero;

  // fragment tuples live across the K-loop; zero-halves written ONCE
  i32x8 afr[4], bfr[4];
#pragma unroll
  for (int q = 0; q < 4; ++q) {
#pragma unroll
    for (int e = 0; e < 8; ++e) { afr[q][e] = 0; bfr[q][e] = 0; }
  }

  STAGE_TILE(0, 0);
  __syncthreads();

#pragma unroll 1
  for (int kt = 0; kt < 16; ++kt) {          // 16 K-tiles of 128 elems
    const int buf = kt & 1;
    const int ktn = (kt < 15) ? kt + 1 : 15; // last iter: junk re-stage, never read
    STAGE_TILE(buf ^ 1, ktn);                // overlaps this tile's compute
    const unsigned char* lb = lds + buf * 16384;
#pragma unroll
    for (int m2 = 0; m2 < 4; ++m2) {
      i32x4 v_ = *reinterpret_cast<const i32x4*>(lb + offA[m2]);
      afr[m2][0] = v_[0]; afr[m2][1] = v_[1]; afr[m2][2] = v_[2]; afr[m2][3] = v_[3];
    }
#pragma unroll
    for (int n2 = 0; n2 < 4; ++n2) {
      i32x4 v_ = *reinterpret_cast<const i32x4*>(lb + offB[n2]);
      bfr[n2][0] = v_[0]; bfr[n2][1] = v_[1]; bfr[n2][2] = v_[2]; bfr[n2][3] = v_[3];
    }
    __builtin_amdgcn_s_setprio(1);
#pragma unroll
    for (int m2 = 0; m2 < 4; ++m2)
#pragma unroll
      for (int n2 = 0; n2 < 4; ++n2)
        acc[m2][n2] = __builtin_amdgcn_mfma_scale_f32_16x16x128_f8f6f4(
            afr[m2], bfr[n2], acc[m2][n2], 4, 4, 0, 127, 0, 127);  // fmt 4 = FP4
    __builtin_amdgcn_s_setprio(0);
    __syncthreads();   // publishes buf^1 + protects buf re-stage next iter
  }

  __syncthreads();

  // C/D layout: col-in-frag = fr, row-in-frag = kg*4 + j (shape-determined)
  // global row = rowBase + wr*64 + m*16 + kg*4 + j
  // global col = colBase + wc*64 + n*16 + fr
  if (isMain) {
    float* shPhi = reinterpret_cast<float*>(lds);
    if (tid < 128) shPhi[tid] = dotv[rowBase + tid] - BETA_F;
    __syncthreads();
#pragma unroll
    for (int m = 0; m < 4; ++m) {
#pragma unroll
      for (int j = 0; j < 4; ++j) {
        int rl = wr * 64 + m * 16 + kg * 4 + j;
        float ph = shPhi[rl];
        float s1 = 0.f, ee = 0.f, ct = 0.f;
#pragma unroll
        for (int n = 0; n < 4; ++n) {
          int gcol = colBase + wc * 64 + n * 16 + fr;
          float c = acc[m][n][j] * INVQ;
          c = fminf(fmaxf(c, -1.f), 1.f);
          if (gcol < NCLS) {
            s1 += c;
            ee += __expf(ALPHA_F * c);
            ct += (c > ph) ? 1.f : 0.f;
          }
        }
        // pack ct (integer, <=4/lane -> <=64 summed) with s1 (|.|<=4/lane):
        // pk = s1 + 4096*ct; rintf(pk/4096) recovers ct EXACTLY (|s1sum|<=64
        // << 2048); s1 quantization <=2^-5 -> ~1e-6 on out[3].
        float pk = s1 + ct * 4096.0f;
#pragma unroll
        for (int o = 1; o < 16; o <<= 1) {
          pk += __shfl_xor(pk, o);
          ee += __shfl_xor(ee, o);
        }
        if (fr == 0) {
          int grow = rowBase + rl;
          float ctv = rintf(pk * (1.0f / 4096.0f));
          float s1v = pk - ctv * 4096.0f;
          atomicAdd(&S1[grow], s1v);
          atomicAdd(&Eacc[grow], ee);
          atomicAdd(&CNT[grow], ctv);
        }
      }
    }
  } else {
    const float wgt = (rowTile == colTile) ? 1.f : 2.f;  // symmetry: off-diag x2
    int* shT = reinterpret_cast<int*>(lds);
    float* redbuf = reinterpret_cast<float*>(lds + 4096);
    if (tid < 128) shT[tid] = tgt[rowBase + tid];
    else if (tid < 256) shT[tid] = tgt[colBase + (tid - 128)];
    __syncthreads();
    float ps = 0.f, als = 0.f, pc = 0.f;
#pragma unroll
    for (int m = 0; m < 4; ++m) {
#pragma unroll
      for (int j = 0; j < 4; ++j) {
        int rl = wr * 64 + m * 16 + kg * 4 + j;
        int tr = shT[rl];
#pragma unroll
        for (int n = 0; n < 4; ++n) {
          int cl = wc * 64 + n * 16 + fr;
          float c = acc[m][n][j] * INVQ;   // sim is NOT clipped in the reference
          als += c;
          if (tr == shT[128 + cl]) { ps += c; pc += 1.f; }
        }
      }
    }
#pragma unroll
    for (int o = 1; o < 64; o <<= 1) {
      ps  += __shfl_xor(ps, o);
      als += __shfl_xor(als, o);
      pc  += __shfl_xor(pc, o);
    }
    if (lane == 0) {
      redbuf[wid * 3 + 0] = ps;
      redbuf[wid * 3 + 1] = als;
      redbuf[wid * 3 + 2] = pc;
    }
    __syncthreads();
    if (tid == 0) {
      float p = 0.f, a = 0.f, c2 = 0.f;
      for (int w = 0; w < 4; ++w) {
        p += redbuf[w * 3 + 0];
        a += redbuf[w * 3 + 1];
        c2 += redbuf[w * 3 + 2];
      }
      atomicAdd(&simAcc[0], wgt * p);
      atomicAdd(&simAcc[1], wgt * a);
      atomicAdd(&simAcc[2], wgt * c2);
    }
  }
}

__global__ void finalize_kernel(const float* __restrict__ dotv, const float* __restrict__ S1,
                                const float* __restrict__ Eacc, const float* __restrict__ CNT,
                                const float* __restrict__ simAcc, float* __restrict__ out) {
  __shared__ float sh[5][1024];
  int tid = threadIdx.x;
  float sum_posc = 0.f, sum_s1 = 0.f, loss_sum = 0.f, mask_cnt = 0.f, correct = 0.f;
  for (int i = tid; i < NROWS; i += 1024) {
    float d = dotv[i];
    float posc = fminf(fmaxf(d, -1.f), 1.f);   // pos_cos (clipped target cos)
    float phi = d - BETA_F;
    sum_posc += posc;
    sum_s1 += S1[i];
    float e = Eacc[i] - __expf(ALPHA_F * posc);   // exclude target column
    float cexcl = CNT[i] - 1.f;                   // target always counted (margin = BETA)
    float per = -phi + __logf(e) / ALPHA_F;
    if (cexcl > 0.5f) { loss_sum += per; mask_cnt += 1.f; }
    else correct += 1.f;                          // pred == target iff no non-target col > phi
  }
  sh[0][tid] = sum_posc; sh[1][tid] = sum_s1; sh[2][tid] = loss_sum;
  sh[3][tid] = mask_cnt; sh[4][tid] = correct;
  __syncthreads();
  for (int s = 512; s > 0; s >>= 1) {
    if (tid < s)
      for (int q = 0; q < 5; ++q) sh[q][tid] += sh[q][tid + s];
    __syncthreads();
  }
  if (tid == 0) {
    float posS = sh[0][0], s1S = sh[1][0], lossS = sh[2][0], maskS = sh[3][0], corr = sh[4][0];
    out[0] = lossS / fmaxf(maskS, 1.f);
    out[1] = corr / (float)NROWS;
    out[2] = posS / (float)NROWS;
    out[3] = (s1S - posS) / ((float)NROWS * (float)(NCLS - 1));
    float pos = simAcc[0], all = simAcc[1], pcnt = simAcc[2];
    out[4] = pos / pcnt;
    out[5] = (all - pos) / ((float)NROWS * (float)NROWS - pcnt);
  }
}

extern "C" void kernel_launch(void* const* d_in, const int* in_sizes, int n_in,
                              void* d_out, int out_size, void* d_ws, size_t ws_size,
                              hipStream_t stream) {
  const float* X  = (const float*)d_in[0];   // inputs  [4096][2048] f32
  const int*   tg = (const int*)d_in[1];     // targets [4096] i32
  const float* Kn = (const float*)d_in[2];   // kernel  [10000][2048] f32
  float* out = (float*)d_out;

  char* w = (char*)d_ws;
  unsigned char* f4A = (unsigned char*)w;                  // 4096*1024 B fp4
  unsigned char* f4B = f4A + (size_t)NROWS * DIMB;         // 10000*1024 B fp4
  float* dotv   = (float*)(w + (size_t)NROWS * DIMB + (size_t)NCLS * DIMB);
  float* S1     = dotv + NROWS;
  float* Eacc   = S1 + NROWS;
  float* CNT    = Eacc + NROWS;
  float* simAcc = CNT + NROWS;

  hipMemsetAsync(S1, 0, (3 * NROWS + 4) * sizeof(float), stream);

  const int nA8 = NROWS * DIM / 8, nT8 = nA8 + NCLS * DIM / 8;
  // merged prep: 2048 cast blocks + 1024 gather-dot blocks
  prep_kernel<<<3072, 256, 0, stream>>>(X, Kn, tg, (unsigned int*)f4A,
                                        (unsigned int*)f4B, dotv, nA8, nT8);

  // merged: 2528 main blocks (79x32, cols clamped+masked past 10000)
  //       +  528 sim triangle blocks (off-diag weighted x2)
  gemm_kernel<<<NMAIN_BLK + NSIM_BLK, 256, 0, stream>>>(
      f4A, f4B, dotv, tg, S1, Eacc, CNT, simAcc);

  finalize_kernel<<<1, 1024, 0, stream>>>(dotv, S1, Eacc, CNT, simAcc, out);
}